// Round 1
// baseline (324.165 us; speedup 1.0000x reference)
//
#include <hip/hip_runtime.h>
#include <hip/hip_bf16.h>
#include <cstddef>

// ----------------------------------------------------------------------------
// AttentionFusion: additive (Bahdanau) cross-attention + FFN + LN + time-mean
// Round 0: correct fp32 baseline. GEMMs on vector ALU (64x64 tiles).
// Key algebraic simplifications:
//   - b2 (per-head scalar added to scores) is softmax-invariant -> dropped.
//   - b1 folded into sx at GEMM epilogue.
//   - LN + mean over t: out[b,d] = g[d]*(Sum_t x*rsig - Sum_t mu*rsig)/128 + lnb[d]
// ----------------------------------------------------------------------------

#define D_  768
#define HD_ 768
#define NH_ 4
#define B_  4
#define T1_ 128
#define T2_ 128
#define M_  (B_*T1_)      // 512 rows of speech-side
#define LN_EPS_ 1e-5f

// ---------------- generic 64x64 tiled fp32 GEMM body ----------------
// C[m0.., n0..] (64x64 tile) = A[M,K](lda) @ B[K,N](ldb) + bias, opt relu.
// 256 threads, 4x4 micro-tile, BK=16. K multiple of 16. M,N multiple of 64.
template<bool RELU>
__device__ __forceinline__ void gemm_body(const float* __restrict__ A, int lda,
                                          const float* __restrict__ B, int ldb,
                                          const float* __restrict__ bias,
                                          float* __restrict__ C, int ldc,
                                          int K, int m0, int n0)
{
    __shared__ float As[16][64];   // [k][m] (K-major so A frag is float4)
    __shared__ float Bs[16][64];   // [k][n]

    const int tid = threadIdx.x;
    const int tx = tid & 15;          // col group (4 cols each)
    const int ty = tid >> 4;          // row group (4 rows each)
    const int arow = tid >> 2;        // A load: row 0..63
    const int akq  = (tid & 3) << 2;  // A load: k quad
    const int bk   = tid >> 4;        // B load: k 0..15
    const int bnq  = (tid & 15) << 2; // B load: n quad

    float acc[4][4];
#pragma unroll
    for (int i = 0; i < 4; i++)
#pragma unroll
        for (int j = 0; j < 4; j++) acc[i][j] = 0.f;

    for (int k0 = 0; k0 < K; k0 += 16) {
        __syncthreads();
        float4 av = *(const float4*)&A[(size_t)(m0 + arow) * lda + k0 + akq];
        As[akq + 0][arow] = av.x;
        As[akq + 1][arow] = av.y;
        As[akq + 2][arow] = av.z;
        As[akq + 3][arow] = av.w;
        *(float4*)&Bs[bk][bnq] = *(const float4*)&B[(size_t)(k0 + bk) * ldb + n0 + bnq];
        __syncthreads();
#pragma unroll
        for (int kk = 0; kk < 16; kk++) {
            float4 a4 = *(const float4*)&As[kk][ty << 2];
            float4 b4 = *(const float4*)&Bs[kk][tx << 2];
            float av_[4] = {a4.x, a4.y, a4.z, a4.w};
            float bv_[4] = {b4.x, b4.y, b4.z, b4.w};
#pragma unroll
            for (int i = 0; i < 4; i++)
#pragma unroll
                for (int j = 0; j < 4; j++)
                    acc[i][j] = fmaf(av_[i], bv_[j], acc[i][j]);
        }
    }

    float4 bv = bias ? *(const float4*)&bias[n0 + (tx << 2)]
                     : make_float4(0.f, 0.f, 0.f, 0.f);
#pragma unroll
    for (int i = 0; i < 4; i++) {
        float4 o;
        o.x = acc[i][0] + bv.x;
        o.y = acc[i][1] + bv.y;
        o.z = acc[i][2] + bv.z;
        o.w = acc[i][3] + bv.w;
        if (RELU) {
            o.x = fmaxf(o.x, 0.f); o.y = fmaxf(o.y, 0.f);
            o.z = fmaxf(o.z, 0.f); o.w = fmaxf(o.w, 0.f);
        }
        *(float4*)&C[(size_t)(m0 + (ty << 2) + i) * ldc + n0 + (tx << 2)] = o;
    }
}

// K1: 8 GEMMs -> sx (b1 folded) and py.  grid (12, 8, 8)
__global__ void gemm_sxpy_kernel(const float* __restrict__ speech,
                                 const float* __restrict__ phon,
                                 const float* __restrict__ W1,
                                 const float* __restrict__ b1,
                                 float* __restrict__ sxb,
                                 float* __restrict__ pyb)
{
    const int n2 = blockIdx.z;
    const int n = n2 & 3;
    const bool ispy = n2 >= 4;
    const float* A = ispy ? phon : speech;
    const float* Bm = W1 + (size_t)n * (2 * D_) * HD_ + (ispy ? (size_t)D_ * HD_ : 0);
    float* C = (ispy ? pyb : sxb) + (size_t)n * M_ * HD_;
    const float* bias = ispy ? nullptr : (b1 + n * HD_);
    gemm_body<false>(A, D_, Bm, HD_, bias, C, HD_, D_, blockIdx.y * 64, blockIdx.x * 64);
}

// K4/K5: plain GEMM.  grid (N/64, M/64)
template<bool RELU>
__global__ void gemm64_kernel(const float* __restrict__ A, int lda,
                              const float* __restrict__ B, int ldb,
                              const float* __restrict__ bias,
                              float* __restrict__ C, int ldc, int K)
{
    gemm_body<RELU>(A, lda, B, ldb, bias, C, ldc, K, blockIdx.y * 64, blockIdx.x * 64);
}

// K2: scores + softmax (per (n, b, t)); writes 0.25-scaled probs.
// grid 2048, 256 threads (4 waves). b2 dropped (softmax-invariant).
__global__ void scores_softmax_kernel(const float* __restrict__ sxb,
                                      const float* __restrict__ pyb,
                                      const float* __restrict__ w2,
                                      float* __restrict__ probs)
{
    const int id = blockIdx.x;        // n*512 + m
    const int n = id >> 9;
    const int m = id & 511;
    const int b = m >> 7;
    const int tid = threadIdx.x;
    const int lane = tid & 63;
    const int wid = tid >> 6;

    const float4* sx4 = (const float4*)(sxb + (size_t)(n * M_ + m) * HD_);
    const float4* w24 = (const float4*)(w2 + (size_t)n * HD_);
    const float4* py4 = (const float4*)(pyb + (size_t)(n * M_ + b * T2_) * HD_);

    float4 sv[3], wv[3];
#pragma unroll
    for (int j = 0; j < 3; j++) {
        sv[j] = sx4[j * 64 + lane];
        wv[j] = w24[j * 64 + lane];
    }

    __shared__ float sc[T2_];
    __shared__ float wred[4];

    for (int i = 0; i < 32; i++) {
        const int s = wid + 4 * i;
        float acc = 0.f;
#pragma unroll
        for (int j = 0; j < 3; j++) {
            float4 pv = py4[(size_t)s * 192 + j * 64 + lane];
            float t0;
            t0 = sv[j].x + pv.x; t0 = fmaxf(t0, 0.f); acc = fmaf(t0, wv[j].x, acc);
            t0 = sv[j].y + pv.y; t0 = fmaxf(t0, 0.f); acc = fmaf(t0, wv[j].y, acc);
            t0 = sv[j].z + pv.z; t0 = fmaxf(t0, 0.f); acc = fmaf(t0, wv[j].z, acc);
            t0 = sv[j].w + pv.w; t0 = fmaxf(t0, 0.f); acc = fmaf(t0, wv[j].w, acc);
        }
#pragma unroll
        for (int off = 32; off; off >>= 1) acc += __shfl_xor(acc, off, 64);
        if (lane == 0) sc[s] = acc;
    }
    __syncthreads();

    // softmax over 128 (threads 0..127 active; all hit barriers)
    float v = (tid < T2_) ? sc[tid] : -1e30f;
    float mx = v;
#pragma unroll
    for (int off = 32; off; off >>= 1) mx = fmaxf(mx, __shfl_xor(mx, off, 64));
    if (lane == 0) wred[wid] = mx;
    __syncthreads();
    mx = fmaxf(wred[0], wred[1]);
    __syncthreads();
    float e = (tid < T2_) ? expf(v - mx) : 0.f;
    float sum = e;
#pragma unroll
    for (int off = 32; off; off >>= 1) sum += __shfl_xor(sum, off, 64);
    if (lane == 0) wred[wid] = sum;
    __syncthreads();
    const float tot = wred[0] + wred[1];
    if (tid < T2_)
        probs[(size_t)id * T2_ + tid] = e / tot * 0.25f;
}

// K3: attn = sum_n probs; context = attn @ phoneme; write fused=[speech,ctx].
// grid 512, 256 threads.
__global__ void context_fused_kernel(const float* __restrict__ probs,
                                     const float* __restrict__ phon,
                                     const float* __restrict__ speech,
                                     float* __restrict__ fused)
{
    const int m = blockIdx.x;
    const int b = m >> 7;
    const int tid = threadIdx.x;
    __shared__ float attn[T2_];
    if (tid < T2_) {
        float a = 0.f;
#pragma unroll
        for (int n = 0; n < NH_; n++)
            a += probs[(size_t)(n * M_ + m) * T2_ + tid];
        attn[tid] = a;
    }
    __syncthreads();
    const float* ph = phon + (size_t)b * T2_ * D_;
#pragma unroll
    for (int j = 0; j < 3; j++) {
        const int d = tid + 256 * j;
        float acc = 0.f;
#pragma unroll 8
        for (int s = 0; s < T2_; s++)
            acc = fmaf(attn[s], ph[(size_t)s * D_ + d], acc);
        fused[(size_t)m * (2 * D_) + d] = speech[(size_t)m * D_ + d];
        fused[(size_t)m * (2 * D_) + D_ + d] = acc;
    }
}

// K6a: per-row LN stats. One wave per row; grid 128 x 256 threads.
__global__ void ln_stats_kernel(const float* __restrict__ x,
                                float* __restrict__ mu, float* __restrict__ rsig)
{
    const int row = blockIdx.x * 4 + (threadIdx.x >> 6);
    const int lane = threadIdx.x & 63;
    const float4* x4 = (const float4*)(x + (size_t)row * D_);
    float s = 0.f, ss = 0.f;
#pragma unroll
    for (int j = 0; j < 3; j++) {
        float4 v = x4[j * 64 + lane];
        s += v.x + v.y + v.z + v.w;
        ss += v.x * v.x + v.y * v.y + v.z * v.z + v.w * v.w;
    }
#pragma unroll
    for (int off = 32; off; off >>= 1) {
        s += __shfl_xor(s, off, 64);
        ss += __shfl_xor(ss, off, 64);
    }
    if (lane == 0) {
        const float m_ = s * (1.f / D_);
        const float var = ss * (1.f / D_) - m_ * m_;
        mu[row] = m_;
        rsig[row] = rsqrtf(var + LN_EPS_);
    }
}

// K6b: out[b,d] = g[d]*(Sum_t x*rsig - Sum_t mu*rsig)/T1 + lnb[d]. grid 4.
__global__ void ln_mean_kernel(const float* __restrict__ x,
                               const float* __restrict__ mu,
                               const float* __restrict__ rsig,
                               const float* __restrict__ g,
                               const float* __restrict__ lb,
                               float* __restrict__ out)
{
    const int b = blockIdx.x;
    const int tid = threadIdx.x;
    __shared__ float rs[T1_];
    __shared__ float red[256];
    float pr = 0.f;
    if (tid < T1_) {
        const float r = rsig[b * T1_ + tid];
        rs[tid] = r;
        pr = mu[b * T1_ + tid] * r;
    }
    red[tid] = pr;
    __syncthreads();
    for (int st = 128; st; st >>= 1) {
        if (tid < st) red[tid] += red[tid + st];
        __syncthreads();
    }
    const float S = red[0];
    const float* xb = x + (size_t)b * T1_ * D_;
#pragma unroll
    for (int j = 0; j < 3; j++) {
        const int d = tid + 256 * j;
        float acc = 0.f;
#pragma unroll 8
        for (int t = 0; t < T1_; t++)
            acc = fmaf(xb[(size_t)t * D_ + d], rs[t], acc);
        out[b * D_ + d] = g[d] * (acc - S) * (1.f / T1_) + lb[d];
    }
}

extern "C" void kernel_launch(void* const* d_in, const int* in_sizes, int n_in,
                              void* d_out, int out_size, void* d_ws, size_t ws_size,
                              hipStream_t stream)
{
    const float* speech = (const float*)d_in[0];   // (4,128,768)
    const float* phon   = (const float*)d_in[1];   // (4,128,768)
    const float* W1     = (const float*)d_in[2];   // (4,1536,768)
    const float* b1     = (const float*)d_in[3];   // (4,768)
    const float* w2     = (const float*)d_in[4];   // (4,768)
    // d_in[5] = b2: softmax-invariant, unused
    const float* Wf1    = (const float*)d_in[6];   // (1536,1536)
    const float* bf1    = (const float*)d_in[7];   // (1536,)
    const float* Wf2    = (const float*)d_in[8];   // (1536,768)
    const float* bf2    = (const float*)d_in[9];   // (768,)
    const float* ln_g   = (const float*)d_in[10];  // (768,)
    const float* ln_b   = (const float*)d_in[11];  // (768,)
    float* out = (float*)d_out;                    // (4,768)

    float* ws = (float*)d_ws;
    float* sxb     = ws;                               // 4*512*768
    float* pyb     = sxb + (size_t)NH_ * M_ * HD_;     // 4*512*768
    float* probs   = pyb + (size_t)NH_ * M_ * HD_;     // 4*512*128
    float* fusedb  = probs + (size_t)NH_ * M_ * T2_;   // 512*1536
    float* hbuf    = fusedb + (size_t)M_ * 2 * D_;     // 512*1536
    float* outpre  = hbuf + (size_t)M_ * 2 * HD_;      // 512*768
    float* mub     = outpre + (size_t)M_ * D_;         // 512
    float* rsigb   = mub + M_;                         // 512

    // K1: sx = speech@Wx + b1 ; py = phoneme@Wy
    hipLaunchKernelGGL(gemm_sxpy_kernel, dim3(HD_ / 64, M_ / 64, 8), dim3(256), 0, stream,
                       speech, phon, W1, b1, sxb, pyb);
    // K2: scores + per-head softmax (0.25-scaled)
    hipLaunchKernelGGL(scores_softmax_kernel, dim3(NH_ * M_), dim3(256), 0, stream,
                       sxb, pyb, w2, probs);
    // K3: head-mean, context, fused concat
    hipLaunchKernelGGL(context_fused_kernel, dim3(M_), dim3(256), 0, stream,
                       probs, phon, speech, fusedb);
    // K4: h = relu(fused @ Wf1 + bf1)
    hipLaunchKernelGGL(gemm64_kernel<true>, dim3(2 * HD_ / 64, M_ / 64), dim3(256), 0, stream,
                       fusedb, 2 * D_, Wf1, 2 * HD_, bf1, hbuf, 2 * HD_, 2 * D_);
    // K5: out_pre = h @ Wf2 + bf2
    hipLaunchKernelGGL(gemm64_kernel<false>, dim3(D_ / 64, M_ / 64), dim3(256), 0, stream,
                       hbuf, 2 * HD_, Wf2, D_, bf2, outpre, D_, 2 * HD_);
    // K6a: LN stats
    hipLaunchKernelGGL(ln_stats_kernel, dim3(M_ / 4), dim3(256), 0, stream,
                       outpre, mub, rsigb);
    // K6b: LN apply + mean over t
    hipLaunchKernelGGL(ln_mean_kernel, dim3(B_), dim3(256), 0, stream,
                       outpre, mub, rsigb, ln_g, ln_b, out);
}

// Round 2
// 152.586 us; speedup vs baseline: 2.1245x; 2.1245x over previous
//
#include <hip/hip_runtime.h>
#include <cstddef>

// ----------------------------------------------------------------------------
// AttentionFusion round 1: bf16 MFMA for the three big GEMMs, t-tiled bf16
// scores kernel. b2 dropped (softmax-invariant), b1 folded into sx epilogue,
// head-mean folded into probs (x0.25), LN+time-mean decomposed.
// ----------------------------------------------------------------------------

#define D_  768
#define HD_ 768
#define NH_ 4
#define B_  4
#define T1_ 128
#define T2_ 128
#define M_  (B_*T1_)
#define LN_EPS_ 1e-5f

typedef unsigned short u16;
typedef __bf16 bf16x8 __attribute__((ext_vector_type(8)));
typedef float f32x4 __attribute__((ext_vector_type(4)));

__device__ __forceinline__ u16 f2bf(float f) {
    union { float f; unsigned int u; } v; v.f = f;
    unsigned int u = v.u + (0x7FFFu + ((v.u >> 16) & 1u));
    return (u16)(u >> 16);
}
__device__ __forceinline__ float bf2f(u16 h) {
    union { unsigned int u; float f; } v; v.u = ((unsigned int)h) << 16;
    return v.f;
}

// ---------------- bf16 MFMA GEMM: C[M,N] = A[M,K] @ Bt[N,K]^T + bias --------
// 64x64 tile, BK=32, 256 threads = 4 waves, each wave 32x32 (2x2 frags).
template<bool RELU, bool OUT_BF16>
__device__ __forceinline__ void gemm_mfma_body(
    const u16* __restrict__ A, int lda,
    const u16* __restrict__ Bt, int ldb,
    const float* __restrict__ bias,
    void* __restrict__ C, int ldc, int K, int m0, int n0)
{
    __shared__ __align__(16) u16 As[64][40];   // 32 k + 8 pad (80B rows)
    __shared__ __align__(16) u16 Bs[64][40];

    const int tid = threadIdx.x;
    const int row = tid >> 2;          // 0..63 staging row
    const int kq  = (tid & 3) << 3;    // 0,8,16,24 staging k-offset
    const int lane = tid & 63;
    const int w  = tid >> 6;
    const int wr = (w >> 1) << 5;      // wave row quadrant: 0/32
    const int wc = (w & 1) << 5;       // wave col quadrant: 0/32
    const int l16 = lane & 15;
    const int lk8 = (lane >> 4) << 3;  // k slice 0,8,16,24
    const int r4  = (lane >> 4) << 2;  // C row group

    const u16* aptr = A + (size_t)(m0 + row) * lda + kq;
    const u16* bptr = Bt + (size_t)(n0 + row) * ldb + kq;

    f32x4 acc00 = {0.f,0.f,0.f,0.f}, acc01 = {0.f,0.f,0.f,0.f};
    f32x4 acc10 = {0.f,0.f,0.f,0.f}, acc11 = {0.f,0.f,0.f,0.f};

    uint4 a_nxt = *(const uint4*)aptr;
    uint4 b_nxt = *(const uint4*)bptr;

    for (int k0 = 0; k0 < K; k0 += 32) {
        __syncthreads();
        *(uint4*)&As[row][kq] = a_nxt;
        *(uint4*)&Bs[row][kq] = b_nxt;
        if (k0 + 32 < K) {
            a_nxt = *(const uint4*)(aptr + k0 + 32);
            b_nxt = *(const uint4*)(bptr + k0 + 32);
        }
        __syncthreads();
        bf16x8 af0 = *(const bf16x8*)&As[wr + l16][lk8];
        bf16x8 af1 = *(const bf16x8*)&As[wr + 16 + l16][lk8];
        bf16x8 bf0 = *(const bf16x8*)&Bs[wc + l16][lk8];
        bf16x8 bf1 = *(const bf16x8*)&Bs[wc + 16 + l16][lk8];
        acc00 = __builtin_amdgcn_mfma_f32_16x16x32_bf16(af0, bf0, acc00, 0, 0, 0);
        acc01 = __builtin_amdgcn_mfma_f32_16x16x32_bf16(af0, bf1, acc01, 0, 0, 0);
        acc10 = __builtin_amdgcn_mfma_f32_16x16x32_bf16(af1, bf0, acc10, 0, 0, 0);
        acc11 = __builtin_amdgcn_mfma_f32_16x16x32_bf16(af1, bf1, acc11, 0, 0, 0);
    }

    // epilogue: D row = (lane>>4)*4 + r, col = lane&15 (m89-verified layout)
#define EPI_FRAG(ACC, MF, NF)                                                  \
    {                                                                          \
        const int gcol = n0 + wc + (NF)*16 + l16;                              \
        const float bv = bias ? bias[gcol] : 0.f;                              \
        _Pragma("unroll")                                                      \
        for (int r = 0; r < 4; r++) {                                          \
            const int grow = m0 + wr + (MF)*16 + r4 + r;                       \
            float v = ACC[r] + bv;                                             \
            if (RELU) v = fmaxf(v, 0.f);                                       \
            if (OUT_BF16) ((u16*)C)[(size_t)grow * ldc + gcol] = f2bf(v);      \
            else          ((float*)C)[(size_t)grow * ldc + gcol] = v;          \
        }                                                                      \
    }
    EPI_FRAG(acc00, 0, 0) EPI_FRAG(acc01, 0, 1)
    EPI_FRAG(acc10, 1, 0) EPI_FRAG(acc11, 1, 1)
#undef EPI_FRAG
}

// K0a: fp32 -> bf16 for speech & phoneme. grid (384, 2)
__global__ void convert_bf16_kernel(const float* __restrict__ s, const float* __restrict__ p,
                                    u16* __restrict__ so, u16* __restrict__ po)
{
    const float* in = blockIdx.y ? p : s;
    u16* out = blockIdx.y ? po : so;
    const int i = (blockIdx.x * 256 + threadIdx.x) * 4;
    float4 v = *(const float4*)(in + i);
    ushort4 o;
    o.x = f2bf(v.x); o.y = f2bf(v.y); o.z = f2bf(v.z); o.w = f2bf(v.w);
    *(ushort4*)(out + i) = o;
}

// K0b: weight transpose+convert: in fp32 [1536][C] -> out bf16 [C][1536].
// grid (48, 48, 6): z<4 -> W1 head z (C=768); z=4 -> Wf1 (C=1536); z=5 -> Wf2 (C=768)
__global__ void transpose_convert_kernel(const float* __restrict__ W1,
                                         const float* __restrict__ Wf1,
                                         const float* __restrict__ Wf2,
                                         u16* __restrict__ w1t,
                                         u16* __restrict__ wf1t,
                                         u16* __restrict__ wf2t)
{
    const int z = blockIdx.z;
    const float* in; u16* out; int C;
    if (z < 4)       { in = W1 + (size_t)z * 1536 * 768; out = w1t + (size_t)z * 768 * 1536; C = 768; }
    else if (z == 4) { in = Wf1; out = wf1t; C = 1536; }
    else             { in = Wf2; out = wf2t; C = 768; }
    const int c0 = blockIdx.x * 32, r0 = blockIdx.y * 32;
    if (c0 >= C) return;
    __shared__ float tile[32][33];
    const int t = threadIdx.x;
    const int tr = t >> 3, tc = (t & 7) << 2;
    float4 v = *(const float4*)(in + (size_t)(r0 + tr) * C + c0 + tc);
    tile[tr][tc] = v.x; tile[tr][tc + 1] = v.y; tile[tr][tc + 2] = v.z; tile[tr][tc + 3] = v.w;
    __syncthreads();
    ushort4 o;
    o.x = f2bf(tile[tc + 0][tr]); o.y = f2bf(tile[tc + 1][tr]);
    o.z = f2bf(tile[tc + 2][tr]); o.w = f2bf(tile[tc + 3][tr]);
    *(ushort4*)(out + (size_t)(c0 + tr) * 1536 + r0 + tc) = o;
}

// K1: 8 batched GEMMs -> sx (b1 folded, bf16) and py (bf16). grid (12, 8, 8)
__global__ void gemm_sxpy_kernel(const u16* __restrict__ sp, const u16* __restrict__ ph,
                                 const u16* __restrict__ w1t, const float* __restrict__ b1,
                                 u16* __restrict__ sx, u16* __restrict__ py)
{
    const int z = blockIdx.z;
    const int n = z & 3;
    const bool ispy = z >= 4;
    const u16* A  = ispy ? ph : sp;
    const u16* Bt = w1t + (size_t)n * 768 * 1536 + (ispy ? 768 : 0);
    u16* C = (ispy ? py : sx) + (size_t)n * M_ * HD_;
    const float* bias = ispy ? nullptr : (b1 + n * HD_);
    gemm_mfma_body<false, true>(A, 768, Bt, 1536, bias, C, HD_, 768,
                                blockIdx.y * 64, blockIdx.x * 64);
}

// K4/K5 plain GEMM. grid (N/64, M/64)
template<bool RELU, bool OUT_BF16>
__global__ void gemm_mfma_kernel(const u16* __restrict__ A, int lda,
                                 const u16* __restrict__ Bt, int ldb,
                                 const float* __restrict__ bias,
                                 void* __restrict__ C, int ldc, int K)
{
    gemm_mfma_body<RELU, OUT_BF16>(A, lda, Bt, ldb, bias, C, ldc, K,
                                   blockIdx.y * 64, blockIdx.x * 64);
}

// K2: scores + softmax for 4 t-rows per block. grid 512 (n,b,tq), 256 threads.
__global__ void scores_softmax_kernel(const u16* __restrict__ sxb,
                                      const u16* __restrict__ pyb,
                                      const float* __restrict__ w2,
                                      float* __restrict__ probs)
{
    const int id = blockIdx.x;
    const int n = id >> 7;
    const int b = (id >> 5) & 3;
    const int t0 = (id & 31) * 4;
    const int tid = threadIdx.x;
    const int lane = tid & 63;
    const int wid = tid >> 6;

    const u16* sxr = sxb + (size_t)(n * M_ + b * T1_ + t0) * HD_;
    float sv[4][12], wv[12];
#pragma unroll
    for (int r = 0; r < 4; r++)
#pragma unroll
        for (int j = 0; j < 3; j++) {
            ushort4 u = *(const ushort4*)(sxr + r * HD_ + (j * 64 + lane) * 4);
            sv[r][j * 4 + 0] = bf2f(u.x); sv[r][j * 4 + 1] = bf2f(u.y);
            sv[r][j * 4 + 2] = bf2f(u.z); sv[r][j * 4 + 3] = bf2f(u.w);
        }
#pragma unroll
    for (int j = 0; j < 3; j++) {
        float4 w4 = *(const float4*)(w2 + n * HD_ + (j * 64 + lane) * 4);
        wv[j * 4 + 0] = w4.x; wv[j * 4 + 1] = w4.y; wv[j * 4 + 2] = w4.z; wv[j * 4 + 3] = w4.w;
    }

    const u16* pyr = pyb + (size_t)(n * M_ + b * T2_) * HD_;
    __shared__ float sc[4][T2_];

    for (int i = 0; i < 32; i++) {
        const int s = (wid << 5) | i;
        float pv[12];
#pragma unroll
        for (int j = 0; j < 3; j++) {
            ushort4 u = *(const ushort4*)(pyr + (size_t)s * HD_ + (j * 64 + lane) * 4);
            pv[j * 4 + 0] = bf2f(u.x); pv[j * 4 + 1] = bf2f(u.y);
            pv[j * 4 + 2] = bf2f(u.z); pv[j * 4 + 3] = bf2f(u.w);
        }
        float acc[4] = {0.f, 0.f, 0.f, 0.f};
#pragma unroll
        for (int r = 0; r < 4; r++)
#pragma unroll
            for (int j = 0; j < 12; j++)
                acc[r] = fmaf(fmaxf(sv[r][j] + pv[j], 0.f), wv[j], acc[r]);
#pragma unroll
        for (int r = 0; r < 4; r++) {
            float a = acc[r];
#pragma unroll
            for (int off = 32; off; off >>= 1) a += __shfl_xor(a, off, 64);
            if (lane == 0) sc[r][s] = a;
        }
    }
    __syncthreads();

    // wave wid finishes row wid: softmax over 128, write 0.25-scaled probs
    {
        const int r = wid;
        const float v0 = sc[r][lane], v1 = sc[r][lane + 64];
        float mx = fmaxf(v0, v1);
#pragma unroll
        for (int off = 32; off; off >>= 1) mx = fmaxf(mx, __shfl_xor(mx, off, 64));
        const float e0 = expf(v0 - mx), e1 = expf(v1 - mx);
        float sm = e0 + e1;
#pragma unroll
        for (int off = 32; off; off >>= 1) sm += __shfl_xor(sm, off, 64);
        const float inv = 0.25f / sm;
        const size_t base = ((size_t)n * M_ + b * T1_ + t0 + r) * T2_;
        probs[base + lane] = e0 * inv;
        probs[base + 64 + lane] = e1 * inv;
    }
}

// K3: attn = sum_n probs; context = attn @ phoneme; fused = [speech, ctx] bf16.
__global__ void context_fused_kernel(const float* __restrict__ probs,
                                     const float* __restrict__ phon,
                                     const float* __restrict__ speech,
                                     u16* __restrict__ fused)
{
    const int m = blockIdx.x;
    const int b = m >> 7;
    const int tid = threadIdx.x;
    __shared__ float attn[T2_];
    if (tid < T2_) {
        float a = 0.f;
#pragma unroll
        for (int n = 0; n < NH_; n++)
            a += probs[(size_t)(n * M_ + m) * T2_ + tid];
        attn[tid] = a;
    }
    __syncthreads();
    const float* ph = phon + (size_t)b * T2_ * D_;
#pragma unroll
    for (int j = 0; j < 3; j++) {
        const int d = tid + 256 * j;
        float acc = 0.f;
#pragma unroll 8
        for (int s = 0; s < T2_; s++)
            acc = fmaf(attn[s], ph[(size_t)s * D_ + d], acc);
        fused[(size_t)m * (2 * D_) + d] = f2bf(speech[(size_t)m * D_ + d]);
        fused[(size_t)m * (2 * D_) + D_ + d] = f2bf(acc);
    }
}

// K6a: per-row LN stats. grid 128 x 256.
__global__ void ln_stats_kernel(const float* __restrict__ x,
                                float* __restrict__ mu, float* __restrict__ rsig)
{
    const int row = blockIdx.x * 4 + (threadIdx.x >> 6);
    const int lane = threadIdx.x & 63;
    const float4* x4 = (const float4*)(x + (size_t)row * D_);
    float s = 0.f, ss = 0.f;
#pragma unroll
    for (int j = 0; j < 3; j++) {
        float4 v = x4[j * 64 + lane];
        s += v.x + v.y + v.z + v.w;
        ss += v.x * v.x + v.y * v.y + v.z * v.z + v.w * v.w;
    }
#pragma unroll
    for (int off = 32; off; off >>= 1) {
        s += __shfl_xor(s, off, 64);
        ss += __shfl_xor(ss, off, 64);
    }
    if (lane == 0) {
        const float m_ = s * (1.f / D_);
        const float var = ss * (1.f / D_) - m_ * m_;
        mu[row] = m_;
        rsig[row] = rsqrtf(var + LN_EPS_);
    }
}

// K6b: out[b,d] = g[d]*(Sum_t x*rsig - Sum_t mu*rsig)/T1 + lnb[d]. grid 4.
__global__ void ln_mean_kernel(const float* __restrict__ x,
                               const float* __restrict__ mu,
                               const float* __restrict__ rsig,
                               const float* __restrict__ g,
                               const float* __restrict__ lb,
                               float* __restrict__ out)
{
    const int b = blockIdx.x;
    const int tid = threadIdx.x;
    __shared__ float rs[T1_];
    __shared__ float red[256];
    float pr = 0.f;
    if (tid < T1_) {
        const float r = rsig[b * T1_ + tid];
        rs[tid] = r;
        pr = mu[b * T1_ + tid] * r;
    }
    red[tid] = pr;
    __syncthreads();
    for (int st = 128; st; st >>= 1) {
        if (tid < st) red[tid] += red[tid + st];
        __syncthreads();
    }
    const float S = red[0];
    const float* xb = x + (size_t)b * T1_ * D_;
#pragma unroll
    for (int j = 0; j < 3; j++) {
        const int d = tid + 256 * j;
        float acc = 0.f;
#pragma unroll 8
        for (int t = 0; t < T1_; t++)
            acc = fmaf(xb[(size_t)t * D_ + d], rs[t], acc);
        out[b * D_ + d] = g[d] * (acc - S) * (1.f / T1_) + lb[d];
    }
}

extern "C" void kernel_launch(void* const* d_in, const int* in_sizes, int n_in,
                              void* d_out, int out_size, void* d_ws, size_t ws_size,
                              hipStream_t stream)
{
    const float* speech = (const float*)d_in[0];
    const float* phon   = (const float*)d_in[1];
    const float* W1     = (const float*)d_in[2];
    const float* b1     = (const float*)d_in[3];
    const float* w2     = (const float*)d_in[4];
    // d_in[5] = b2: softmax-invariant, unused
    const float* Wf1    = (const float*)d_in[6];
    const float* bf1    = (const float*)d_in[7];
    const float* Wf2    = (const float*)d_in[8];
    const float* bf2    = (const float*)d_in[9];
    const float* ln_g   = (const float*)d_in[10];
    const float* ln_b   = (const float*)d_in[11];
    float* out = (float*)d_out;

    char* w = (char*)d_ws;
    auto alloc = [&](size_t bytes) { char* p = w; w += (bytes + 1023) & ~(size_t)1023; return p; };
    u16* sp_bf  = (u16*)alloc((size_t)M_ * D_ * 2);
    u16* ph_bf  = (u16*)alloc((size_t)M_ * D_ * 2);
    u16* w1t    = (u16*)alloc((size_t)NH_ * 768 * 1536 * 2);
    u16* wf1t   = (u16*)alloc((size_t)1536 * 1536 * 2);
    u16* wf2t   = (u16*)alloc((size_t)768 * 1536 * 2);
    u16* sxb    = (u16*)alloc((size_t)NH_ * M_ * HD_ * 2);
    u16* pyb    = (u16*)alloc((size_t)NH_ * M_ * HD_ * 2);
    float* probs  = (float*)alloc((size_t)NH_ * M_ * T2_ * 4);
    u16* fusedb = (u16*)alloc((size_t)M_ * 2 * D_ * 2);
    u16* hbuf   = (u16*)alloc((size_t)M_ * 2 * HD_ * 2);
    float* outpre = (float*)alloc((size_t)M_ * D_ * 4);
    float* mub    = (float*)alloc(M_ * 4);
    float* rsigb  = (float*)alloc(M_ * 4);

    // K0a: inputs -> bf16
    hipLaunchKernelGGL(convert_bf16_kernel, dim3(384, 2), dim3(256), 0, stream,
                       speech, phon, sp_bf, ph_bf);
    // K0b: weights -> transposed bf16
    hipLaunchKernelGGL(transpose_convert_kernel, dim3(48, 48, 6), dim3(256), 0, stream,
                       W1, Wf1, Wf2, w1t, wf1t, wf2t);
    // K1: sx = speech@Wx + b1 ; py = phoneme@Wy (bf16 out)
    hipLaunchKernelGGL(gemm_sxpy_kernel, dim3(HD_ / 64, M_ / 64, 8), dim3(256), 0, stream,
                       sp_bf, ph_bf, w1t, b1, sxb, pyb);
    // K2: scores + per-head softmax (0.25-scaled)
    hipLaunchKernelGGL(scores_softmax_kernel, dim3(512), dim3(256), 0, stream,
                       sxb, pyb, w2, probs);
    // K3: head-mean, context, fused concat (bf16)
    hipLaunchKernelGGL(context_fused_kernel, dim3(M_), dim3(256), 0, stream,
                       probs, phon, speech, fusedb);
    // K4: h = relu(fused @ Wf1 + bf1) (bf16 out)
    hipLaunchKernelGGL((gemm_mfma_kernel<true, true>), dim3(2 * HD_ / 64, M_ / 64), dim3(256), 0, stream,
                       fusedb, 2 * D_, wf1t, 1536, bf1, hbuf, 2 * HD_, 2 * D_);
    // K5: out_pre = h @ Wf2 + bf2 (f32 out)
    hipLaunchKernelGGL((gemm_mfma_kernel<false, false>), dim3(D_ / 64, M_ / 64), dim3(256), 0, stream,
                       hbuf, 2 * HD_, wf2t, 1536, bf2, outpre, D_, 2 * HD_);
    // K6a: LN stats
    hipLaunchKernelGGL(ln_stats_kernel, dim3(M_ / 4), dim3(256), 0, stream,
                       outpre, mub, rsigb);
    // K6b: LN apply + mean over t
    hipLaunchKernelGGL(ln_mean_kernel, dim3(B_), dim3(256), 0, stream,
                       outpre, mub, rsigb, ln_g, ln_b, out);
}

// Round 3
// 130.291 us; speedup vs baseline: 2.4880x; 1.1711x over previous
//
#include <hip/hip_runtime.h>
#include <cstddef>

// ----------------------------------------------------------------------------
// AttentionFusion round 2: scores kernel rewritten as s-across-lanes packed-f16
// (no shuffles in inner loop, py transposed [n,b,h,s] f16 produced by K1
// epilogue). GEMMs unchanged from round 1 (bf16 MFMA 64x64 tiles).
// ----------------------------------------------------------------------------

#define D_  768
#define HD_ 768
#define NH_ 4
#define B_  4
#define T1_ 128
#define T2_ 128
#define M_  (B_*T1_)
#define LN_EPS_ 1e-5f

typedef unsigned short u16;
typedef _Float16 f16;
typedef _Float16 f16x2 __attribute__((ext_vector_type(2)));
typedef __bf16 bf16x8 __attribute__((ext_vector_type(8)));
typedef float f32x4 __attribute__((ext_vector_type(4)));

__device__ __forceinline__ u16 f2bf(float f) {
    union { float f; unsigned int u; } v; v.f = f;
    unsigned int u = v.u + (0x7FFFu + ((v.u >> 16) & 1u));
    return (u16)(u >> 16);
}
__device__ __forceinline__ f16x2 bcast2(unsigned int u) {
    return __builtin_bit_cast(f16x2, u);
}
__device__ __forceinline__ u16 f16bits(f16 h) {
    return __builtin_bit_cast(unsigned short, h);
}

// ---------------- bf16 MFMA GEMM: C[M,N] = A[M,K] @ Bt[N,K]^T + bias --------
// MODE: 0 = f32 rows, 1 = bf16 rows, 2 = f16 rows, 3 = f16 transposed (py_t)
template<bool RELU, int MODE>
__device__ __forceinline__ void gemm_mfma_body(
    const u16* __restrict__ A, int lda,
    const u16* __restrict__ Bt, int ldb,
    const float* __restrict__ bias,
    void* __restrict__ C, int ldc, int K, int m0, int n0)
{
    __shared__ __align__(16) u16 As[64][40];
    __shared__ __align__(16) u16 Bs[64][40];

    const int tid = threadIdx.x;
    const int row = tid >> 2;
    const int kq  = (tid & 3) << 3;
    const int lane = tid & 63;
    const int w  = tid >> 6;
    const int wr = (w >> 1) << 5;
    const int wc = (w & 1) << 5;
    const int l16 = lane & 15;
    const int lk8 = (lane >> 4) << 3;
    const int r4  = (lane >> 4) << 2;

    const u16* aptr = A + (size_t)(m0 + row) * lda + kq;
    const u16* bptr = Bt + (size_t)(n0 + row) * ldb + kq;

    f32x4 acc00 = {0.f,0.f,0.f,0.f}, acc01 = {0.f,0.f,0.f,0.f};
    f32x4 acc10 = {0.f,0.f,0.f,0.f}, acc11 = {0.f,0.f,0.f,0.f};

    uint4 a_nxt = *(const uint4*)aptr;
    uint4 b_nxt = *(const uint4*)bptr;

    for (int k0 = 0; k0 < K; k0 += 32) {
        __syncthreads();
        *(uint4*)&As[row][kq] = a_nxt;
        *(uint4*)&Bs[row][kq] = b_nxt;
        if (k0 + 32 < K) {
            a_nxt = *(const uint4*)(aptr + k0 + 32);
            b_nxt = *(const uint4*)(bptr + k0 + 32);
        }
        __syncthreads();
        bf16x8 af0 = *(const bf16x8*)&As[wr + l16][lk8];
        bf16x8 af1 = *(const bf16x8*)&As[wr + 16 + l16][lk8];
        bf16x8 bf0 = *(const bf16x8*)&Bs[wc + l16][lk8];
        bf16x8 bf1 = *(const bf16x8*)&Bs[wc + 16 + l16][lk8];
        acc00 = __builtin_amdgcn_mfma_f32_16x16x32_bf16(af0, bf0, acc00, 0, 0, 0);
        acc01 = __builtin_amdgcn_mfma_f32_16x16x32_bf16(af0, bf1, acc01, 0, 0, 0);
        acc10 = __builtin_amdgcn_mfma_f32_16x16x32_bf16(af1, bf0, acc10, 0, 0, 0);
        acc11 = __builtin_amdgcn_mfma_f32_16x16x32_bf16(af1, bf1, acc11, 0, 0, 0);
    }

#define EPI_FRAG(ACC, MF, NF)                                                  \
    {                                                                          \
        const int gcol = n0 + wc + (NF)*16 + l16;                              \
        const float bv = bias ? bias[gcol] : 0.f;                              \
        float v_[4];                                                           \
        _Pragma("unroll")                                                      \
        for (int r = 0; r < 4; r++) {                                          \
            float v = ACC[r] + bv;                                             \
            if (RELU) v = fmaxf(v, 0.f);                                       \
            v_[r] = v;                                                         \
        }                                                                      \
        const int grow0 = m0 + wr + (MF)*16 + r4;                              \
        if (MODE == 3) {                                                       \
            /* py_t[b][h][s]: C = base for head n; b = grow0>>7, s = grow0&127 */ \
            u16* dst = (u16*)C + (size_t)(grow0 >> 7) * (768 * 128)            \
                     + (size_t)gcol * 128 + (grow0 & 127);                     \
            ushort4 pk4;                                                       \
            pk4.x = f16bits((f16)v_[0]); pk4.y = f16bits((f16)v_[1]);          \
            pk4.z = f16bits((f16)v_[2]); pk4.w = f16bits((f16)v_[3]);          \
            *(ushort4*)dst = pk4;                                              \
        } else {                                                               \
            _Pragma("unroll")                                                  \
            for (int r = 0; r < 4; r++) {                                      \
                const size_t off = (size_t)(grow0 + r) * ldc + gcol;           \
                if (MODE == 0) ((float*)C)[off] = v_[r];                       \
                else if (MODE == 1) ((u16*)C)[off] = f2bf(v_[r]);              \
                else ((u16*)C)[off] = f16bits((f16)v_[r]);                     \
            }                                                                  \
        }                                                                      \
    }
    EPI_FRAG(acc00, 0, 0) EPI_FRAG(acc01, 0, 1)
    EPI_FRAG(acc10, 1, 0) EPI_FRAG(acc11, 1, 1)
#undef EPI_FRAG
}

// K0a: fp32 -> bf16 for speech & phoneme. grid (384, 2)
__global__ void convert_bf16_kernel(const float* __restrict__ s, const float* __restrict__ p,
                                    u16* __restrict__ so, u16* __restrict__ po)
{
    const float* in = blockIdx.y ? p : s;
    u16* out = blockIdx.y ? po : so;
    const int i = (blockIdx.x * 256 + threadIdx.x) * 4;
    float4 v = *(const float4*)(in + i);
    ushort4 o;
    o.x = f2bf(v.x); o.y = f2bf(v.y); o.z = f2bf(v.z); o.w = f2bf(v.w);
    *(ushort4*)(out + i) = o;
}

// K0b: weight transpose+convert: fp32 [1536][C] -> bf16 [C][1536].
__global__ void transpose_convert_kernel(const float* __restrict__ W1,
                                         const float* __restrict__ Wf1,
                                         const float* __restrict__ Wf2,
                                         u16* __restrict__ w1t,
                                         u16* __restrict__ wf1t,
                                         u16* __restrict__ wf2t)
{
    const int z = blockIdx.z;
    const float* in; u16* out; int C;
    if (z < 4)       { in = W1 + (size_t)z * 1536 * 768; out = w1t + (size_t)z * 768 * 1536; C = 768; }
    else if (z == 4) { in = Wf1; out = wf1t; C = 1536; }
    else             { in = Wf2; out = wf2t; C = 768; }
    const int c0 = blockIdx.x * 32, r0 = blockIdx.y * 32;
    if (c0 >= C) return;
    __shared__ float tile[32][33];
    const int t = threadIdx.x;
    const int tr = t >> 3, tc = (t & 7) << 2;
    float4 v = *(const float4*)(in + (size_t)(r0 + tr) * C + c0 + tc);
    tile[tr][tc] = v.x; tile[tr][tc + 1] = v.y; tile[tr][tc + 2] = v.z; tile[tr][tc + 3] = v.w;
    __syncthreads();
    ushort4 o;
    o.x = f2bf(tile[tc + 0][tr]); o.y = f2bf(tile[tc + 1][tr]);
    o.z = f2bf(tile[tc + 2][tr]); o.w = f2bf(tile[tc + 3][tr]);
    *(ushort4*)(out + (size_t)(c0 + tr) * 1536 + r0 + tc) = o;
}

// K1: 8 GEMMs -> sx (b1 folded, f16 rows) and py_t (f16 transposed). grid (12,8,8)
__global__ void gemm_sxpy_kernel(const u16* __restrict__ sp, const u16* __restrict__ ph,
                                 const u16* __restrict__ w1t, const float* __restrict__ b1,
                                 u16* __restrict__ sxf, u16* __restrict__ pyt)
{
    const int z = blockIdx.z;
    const int n = z & 3;
    const bool ispy = z >= 4;
    const u16* Bt = w1t + (size_t)n * 768 * 1536 + (ispy ? 768 : 0);
    if (!ispy) {
        gemm_mfma_body<false, 2>(sp, 768, Bt, 1536, b1 + n * HD_,
                                 sxf + (size_t)n * M_ * HD_, HD_, 768,
                                 blockIdx.y * 64, blockIdx.x * 64);
    } else {
        gemm_mfma_body<false, 3>(ph, 768, Bt, 1536, nullptr,
                                 pyt + (size_t)n * 4 * 768 * 128, 0, 768,
                                 blockIdx.y * 64, blockIdx.x * 64);
    }
}

template<bool RELU, int MODE>
__global__ void gemm_mfma_kernel(const u16* __restrict__ A, int lda,
                                 const u16* __restrict__ Bt, int ldb,
                                 const float* __restrict__ bias,
                                 void* __restrict__ C, int ldc, int K)
{
    gemm_mfma_body<RELU, MODE>(A, lda, Bt, ldb, bias, C, ldc, K,
                               blockIdx.y * 64, blockIdx.x * 64);
}

// ---------------------------------------------------------------------------
// K2 v2: packed-f16, s-across-lanes scores + softmax.
// grid 256 = (n, b, t8): 4 waves x 2 t-rows each, 128 s as 2 per lane.
// ---------------------------------------------------------------------------
__global__ __launch_bounds__(256) void scores_softmax_kernel(
    const u16* __restrict__ sxf,     // f16 [n][512][768]
    const u16* __restrict__ pyt,     // f16 [n][b][768][128]
    const float* __restrict__ w2,    // f32 [n][768]
    float* __restrict__ probs)       // f32 [n][512][128], 0.25-scaled
{
    const int bid = blockIdx.x;
    const int n = bid >> 6, b = (bid >> 4) & 3, t0 = (bid & 15) * 8;
    const int tid = threadIdx.x, lane = tid & 63, w = tid >> 6;

    __shared__ __align__(16) f16x2 sxs[8][768];   // splatted sx rows, 24KB
    __shared__ __align__(16) f16x2 w2s[768];      // splatted w2, 3KB

    // stage sx (8 rows x 768): 1536 quad-units, 6 per thread
    for (int q = 0; q < 6; q++) {
        const int u = tid + q * 256;
        const int r = u / 192;
        const int h4 = (u % 192) * 4;
        ushort4 v = *(const ushort4*)(sxf + ((size_t)(n * 512 + b * 128 + t0 + r)) * 768 + h4);
        sxs[r][h4 + 0] = bcast2((unsigned)v.x * 0x10001u);
        sxs[r][h4 + 1] = bcast2((unsigned)v.y * 0x10001u);
        sxs[r][h4 + 2] = bcast2((unsigned)v.z * 0x10001u);
        sxs[r][h4 + 3] = bcast2((unsigned)v.w * 0x10001u);
    }
    for (int q = 0; q < 3; q++) {
        const int i = tid + q * 256;
        f16 hv = (f16)w2[n * 768 + i];
        f16x2 s2; s2.x = hv; s2.y = hv;
        w2s[i] = s2;
    }
    __syncthreads();

    const f16x2* pypanel = (const f16x2*)(pyt + ((size_t)((n << 2) | b)) * 768 * 128) + lane;

    float accA0 = 0.f, accA1 = 0.f, accB0 = 0.f, accB1 = 0.f;
    const int rA = 2 * w, rB = 2 * w + 1;

    f16x2 b0[16], b1[16];
#pragma unroll
    for (int j = 0; j < 16; j++) b0[j] = pypanel[(size_t)j * 64];
#pragma unroll
    for (int j = 0; j < 16; j++) b1[j] = pypanel[(size_t)(16 + j) * 64];

    auto compute = [&](const f16x2 (&buf)[16], int hbase) {
        f16x2 aA = {(f16)0, (f16)0}, aB = {(f16)0, (f16)0};
#pragma unroll
        for (int j4 = 0; j4 < 16; j4 += 4) {
            uint4 sau = *(const uint4*)&sxs[rA][hbase + j4];
            uint4 sbu = *(const uint4*)&sxs[rB][hbase + j4];
            uint4 wvu = *(const uint4*)&w2s[hbase + j4];
            const unsigned sa_[4] = {sau.x, sau.y, sau.z, sau.w};
            const unsigned sb_[4] = {sbu.x, sbu.y, sbu.z, sbu.w};
            const unsigned wv_[4] = {wvu.x, wvu.y, wvu.z, wvu.w};
#pragma unroll
            for (int j = 0; j < 4; j++) {
                const f16x2 p = buf[j4 + j];
                const f16x2 wj = bcast2(wv_[j]);
                const f16x2 z = {(f16)0, (f16)0};
                f16x2 ra = __builtin_elementwise_max(bcast2(sa_[j]) + p, z);
                f16x2 rb = __builtin_elementwise_max(bcast2(sb_[j]) + p, z);
                aA = __builtin_elementwise_fma(ra, wj, aA);
                aB = __builtin_elementwise_fma(rb, wj, aB);
            }
        }
        accA0 += (float)aA.x; accA1 += (float)aA.y;
        accB0 += (float)aB.x; accB1 += (float)aB.y;
    };

    for (int hc = 0; hc < 768; hc += 32) {
        compute(b0, hc);
        if (hc + 32 < 768) {
#pragma unroll
            for (int j = 0; j < 16; j++) b0[j] = pypanel[(size_t)(hc + 32 + j) * 64];
        }
        compute(b1, hc + 16);
        if (hc + 48 < 768) {
#pragma unroll
            for (int j = 0; j < 16; j++) b1[j] = pypanel[(size_t)(hc + 48 + j) * 64];
        }
    }

    // per-t softmax across the wave (128 scores = 2 per lane), write 0.25-scaled
#pragma unroll
    for (int which = 0; which < 2; which++) {
        const float s0 = which ? accB0 : accA0;
        const float s1 = which ? accB1 : accA1;
        const int t = t0 + 2 * w + which;
        float mx = fmaxf(s0, s1);
#pragma unroll
        for (int off = 32; off; off >>= 1) mx = fmaxf(mx, __shfl_xor(mx, off, 64));
        const float e0 = expf(s0 - mx), e1 = expf(s1 - mx);
        float sm = e0 + e1;
#pragma unroll
        for (int off = 32; off; off >>= 1) sm += __shfl_xor(sm, off, 64);
        const float inv = 0.25f / sm;
        float2 pr; pr.x = e0 * inv; pr.y = e1 * inv;
        *(float2*)&probs[((size_t)(n * 512 + b * 128 + t)) * 128 + 2 * lane] = pr;
    }
}

// K3: attn = sum_n probs; context = attn @ phoneme; fused = [speech, ctx] bf16.
__global__ void context_fused_kernel(const float* __restrict__ probs,
                                     const float* __restrict__ phon,
                                     const float* __restrict__ speech,
                                     u16* __restrict__ fused)
{
    const int m = blockIdx.x;
    const int b = m >> 7;
    const int tid = threadIdx.x;
    __shared__ float attn[T2_];
    if (tid < T2_) {
        float a = 0.f;
#pragma unroll
        for (int n = 0; n < NH_; n++)
            a += probs[(size_t)(n * M_ + m) * T2_ + tid];
        attn[tid] = a;
    }
    __syncthreads();
    const float* ph = phon + (size_t)b * T2_ * D_;
#pragma unroll
    for (int j = 0; j < 3; j++) {
        const int d = tid + 256 * j;
        float acc = 0.f;
#pragma unroll 8
        for (int s = 0; s < T2_; s++)
            acc = fmaf(attn[s], ph[(size_t)s * D_ + d], acc);
        fused[(size_t)m * (2 * D_) + d] = f2bf(speech[(size_t)m * D_ + d]);
        fused[(size_t)m * (2 * D_) + D_ + d] = f2bf(acc);
    }
}

// K6a: per-row LN stats. grid 128 x 256.
__global__ void ln_stats_kernel(const float* __restrict__ x,
                                float* __restrict__ mu, float* __restrict__ rsig)
{
    const int row = blockIdx.x * 4 + (threadIdx.x >> 6);
    const int lane = threadIdx.x & 63;
    const float4* x4 = (const float4*)(x + (size_t)row * D_);
    float s = 0.f, ss = 0.f;
#pragma unroll
    for (int j = 0; j < 3; j++) {
        float4 v = x4[j * 64 + lane];
        s += v.x + v.y + v.z + v.w;
        ss += v.x * v.x + v.y * v.y + v.z * v.z + v.w * v.w;
    }
#pragma unroll
    for (int off = 32; off; off >>= 1) {
        s += __shfl_xor(s, off, 64);
        ss += __shfl_xor(ss, off, 64);
    }
    if (lane == 0) {
        const float m_ = s * (1.f / D_);
        const float var = ss * (1.f / D_) - m_ * m_;
        mu[row] = m_;
        rsig[row] = rsqrtf(var + LN_EPS_);
    }
}

// K6b: out[b,d] = g[d]*(Sum_t x*rsig - Sum_t mu*rsig)/T1 + lnb[d]. grid 4.
__global__ void ln_mean_kernel(const float* __restrict__ x,
                               const float* __restrict__ mu,
                               const float* __restrict__ rsig,
                               const float* __restrict__ g,
                               const float* __restrict__ lb,
                               float* __restrict__ out)
{
    const int b = blockIdx.x;
    const int tid = threadIdx.x;
    __shared__ float rs[T1_];
    __shared__ float red[256];
    float pr = 0.f;
    if (tid < T1_) {
        const float r = rsig[b * T1_ + tid];
        rs[tid] = r;
        pr = mu[b * T1_ + tid] * r;
    }
    red[tid] = pr;
    __syncthreads();
    for (int st = 128; st; st >>= 1) {
        if (tid < st) red[tid] += red[tid + st];
        __syncthreads();
    }
    const float S = red[0];
    const float* xb = x + (size_t)b * T1_ * D_;
#pragma unroll
    for (int j = 0; j < 3; j++) {
        const int d = tid + 256 * j;
        float acc = 0.f;
#pragma unroll 8
        for (int t = 0; t < T1_; t++)
            acc = fmaf(xb[(size_t)t * D_ + d], rs[t], acc);
        out[b * D_ + d] = g[d] * (acc - S) * (1.f / T1_) + lb[d];
    }
}

extern "C" void kernel_launch(void* const* d_in, const int* in_sizes, int n_in,
                              void* d_out, int out_size, void* d_ws, size_t ws_size,
                              hipStream_t stream)
{
    const float* speech = (const float*)d_in[0];
    const float* phon   = (const float*)d_in[1];
    const float* W1     = (const float*)d_in[2];
    const float* b1     = (const float*)d_in[3];
    const float* w2     = (const float*)d_in[4];
    // d_in[5] = b2: softmax-invariant, unused
    const float* Wf1    = (const float*)d_in[6];
    const float* bf1    = (const float*)d_in[7];
    const float* Wf2    = (const float*)d_in[8];
    const float* bf2    = (const float*)d_in[9];
    const float* ln_g   = (const float*)d_in[10];
    const float* ln_b   = (const float*)d_in[11];
    float* out = (float*)d_out;

    char* w = (char*)d_ws;
    auto alloc = [&](size_t bytes) { char* p = w; w += (bytes + 1023) & ~(size_t)1023; return p; };
    u16* sp_bf  = (u16*)alloc((size_t)M_ * D_ * 2);
    u16* ph_bf  = (u16*)alloc((size_t)M_ * D_ * 2);
    u16* w1t    = (u16*)alloc((size_t)NH_ * 768 * 1536 * 2);
    u16* wf1t   = (u16*)alloc((size_t)1536 * 1536 * 2);
    u16* wf2t   = (u16*)alloc((size_t)768 * 1536 * 2);
    u16* sxf    = (u16*)alloc((size_t)NH_ * M_ * HD_ * 2);   // f16
    u16* pyt    = (u16*)alloc((size_t)NH_ * B_ * 768 * 128 * 2); // f16 transposed
    float* probs  = (float*)alloc((size_t)NH_ * M_ * T2_ * 4);
    u16* fusedb = (u16*)alloc((size_t)M_ * 2 * D_ * 2);
    u16* hbuf   = (u16*)alloc((size_t)M_ * 2 * HD_ * 2);
    float* outpre = (float*)alloc((size_t)M_ * D_ * 4);
    float* mub    = (float*)alloc(M_ * 4);
    float* rsigb  = (float*)alloc(M_ * 4);

    hipLaunchKernelGGL(convert_bf16_kernel, dim3(384, 2), dim3(256), 0, stream,
                       speech, phon, sp_bf, ph_bf);
    hipLaunchKernelGGL(transpose_convert_kernel, dim3(48, 48, 6), dim3(256), 0, stream,
                       W1, Wf1, Wf2, w1t, wf1t, wf2t);
    hipLaunchKernelGGL(gemm_sxpy_kernel, dim3(HD_ / 64, M_ / 64, 8), dim3(256), 0, stream,
                       sp_bf, ph_bf, w1t, b1, sxf, pyt);
    hipLaunchKernelGGL(scores_softmax_kernel, dim3(256), dim3(256), 0, stream,
                       sxf, pyt, w2, probs);
    hipLaunchKernelGGL(context_fused_kernel, dim3(M_), dim3(256), 0, stream,
                       probs, phon, speech, fusedb);
    hipLaunchKernelGGL((gemm_mfma_kernel<true, 1>), dim3(2 * HD_ / 64, M_ / 64), dim3(256), 0, stream,
                       fusedb, 2 * D_, wf1t, 1536, bf1, hbuf, 2 * HD_, 2 * D_);
    hipLaunchKernelGGL((gemm_mfma_kernel<false, 0>), dim3(D_ / 64, M_ / 64), dim3(256), 0, stream,
                       hbuf, 2 * HD_, wf2t, 1536, bf2, outpre, D_, 2 * HD_);
    hipLaunchKernelGGL(ln_stats_kernel, dim3(M_ / 4), dim3(256), 0, stream,
                       outpre, mub, rsigb);
    hipLaunchKernelGGL(ln_mean_kernel, dim3(B_), dim3(256), 0, stream,
                       outpre, mub, rsigb, ln_g, ln_b, out);
}